// Round 1
// baseline (87.131 us; speedup 1.0000x reference)
//
#include <hip/hip_runtime.h>
#include <hip/hip_bf16.h>
#include <cstdint>

#define NV 64
#define NH 128
#define NB 16384
#define NCHUNK 37                 // 8 diag + 28 off-diag + 1 order-1, 64 k each
#define FRAG_ELEMS (NCHUNK * 8192)  // 303104 bf16 = 592 KB in d_ws

typedef __bf16 bf16x8_t __attribute__((ext_vector_type(8)));
typedef float f32x4_t __attribute__((ext_vector_type(4)));
typedef float f32x2_t __attribute__((ext_vector_type(2)));
typedef uint32_t u32x4_t __attribute__((ext_vector_type(4)));
typedef uint32_t u32x2_t __attribute__((ext_vector_type(2)));

__device__ __forceinline__ uint32_t bf16_rne(float f) {
  uint32_t u = __float_as_uint(f);
  return (u + 0x7fffu + ((u >> 16) & 1u)) >> 16;
}

// Pre-pass: build B' in MFMA-B-fragment order, symmetrized group-triangle:
//  chunk c<8 (diag, I=J=c):    B'[h, slot(a,b)] = 0.5*W2[h, I8+a, I8+b]
//  chunk 8..35 (off, I<J):     B'[h, slot(a,b)] = 0.5*(W2[h,i,j]+W2[h,j,i])
//  chunk 36 (order-1):         B'[h, slot=j]    = W1[j, h]
// Fragment (c2 = c*2+jh, fh): lane l holds B'[h = fh*16+(l&15)]
//   [k = slot = jh*32 + (l>>4)*8 + t], elem offset ((c2*8+fh)*512 + l*8 + t).
__global__ void cvt_kernel(const float* __restrict__ w1f,
                           const float* __restrict__ w2f,
                           uint16_t* __restrict__ frag) {
  int tg = blockIdx.x * 256 + threadIdx.x;   // < 74*8*64 = 37888
  int l = tg & 63, fh = (tg >> 6) & 7, c2 = tg >> 9;
  int chunk = c2 >> 1, jh = c2 & 1;
  int h = fh * 16 + (l & 15);
  int kb = jh * 32 + (l >> 4) * 8;
  uint32_t o16[8];
#pragma unroll
  for (int t = 0; t < 8; ++t) {
    int slot = kb + t;
    float v;
    if (chunk < 8) {
      int i = chunk * 8 + (slot >> 3), j = chunk * 8 + (slot & 7);
      v = 0.5f * w2f[h * 4096 + i * 64 + j];
    } else if (chunk < 36) {
      int o = chunk - 8, I = 0;
      while (o >= 7 - I) { o -= 7 - I; ++I; }
      int J = I + 1 + o;
      int i = I * 8 + (slot >> 3), j = J * 8 + (slot & 7);
      v = 0.5f * (w2f[h * 4096 + i * 64 + j] + w2f[h * 4096 + j * 64 + i]);
    } else {
      v = w1f[slot * 128 + h];
    }
    o16[t] = bf16_rne(v);
  }
  uint4 o;
  o.x = (o16[1] << 16) | o16[0];
  o.y = (o16[3] << 16) | o16[2];
  o.z = (o16[5] << 16) | o16[4];
  o.w = (o16[7] << 16) | o16[6];
  *(uint4*)(frag + ((size_t)(c2 * 8 + fh) << 9) + l * 8) = o;
}

// psi[m] = prod_h cos(bias[h] + sum_k A[m,k] B'[h,k]), K = 37*64.
// v2: 32 rows/block (grid 512 -> 2 blocks/CU), 8 waves = 2 row-halves x 4
// h-quarters, ONE m-row per lane -> xb[32] = 64 VGPR (was 128) -> total
// VGPR <= 128 -> 4 waves/SIMD (was 2). Same per-CU MFMA work; depth-1
// register prefetch of B-frags; zero barriers in the K-loop.
__launch_bounds__(512, 4)
__global__ void rbm_kernel(const float* __restrict__ xg,
                           const float* __restrict__ biasg,
                           const __hip_bfloat16* __restrict__ frag,
                           float* __restrict__ outg) {
  __shared__ __align__(16) float xtile[32 * 76];
  __shared__ float part[4][32];

  const int tid  = threadIdx.x;
  const int wv   = tid >> 6;
  const int wm   = wv & 1;     // 16-row half
  const int hq   = wv >> 1;    // h quarter (32 cols)
  const int lane = tid & 63;
  const int c15  = lane & 15;
  const int q    = lane >> 4;
  const int mblk = blockIdx.x * 32;

  // chunk -> (I, J) tables (compile-time folded under full unroll)
  constexpr int CI[36] = {0,1,2,3,4,5,6,7, 0,0,0,0,0,0,0, 1,1,1,1,1,1,
                          2,2,2,2,2, 3,3,3,3, 4,4,4, 5,5, 6};
  constexpr int CJ[36] = {0,1,2,3,4,5,6,7, 1,2,3,4,5,6,7, 2,3,4,5,6,7,
                          3,4,5,6,7, 4,5,6,7, 5,6,7, 6,7, 7};

  // stage x tile (32 rows x 64 f32, stride 76): one float4 per thread
  {
    int row = tid >> 4, col4 = (tid & 15) * 4;
    const float* p = xg + (size_t)(mblk + row) * NV + col4;
    *(float4*)(&xtile[row * 76 + col4]) = *(const float4*)p;
  }
  __syncthreads();

  // this lane's single m-row: LDS base + full row cached in regs (f32 pairs)
  const float* sx = &xtile[(wm * 16 + c15) * 76];
  f32x2_t xb[32];   // xb[g*4+tt] = {x[g*8+2tt], x[g*8+2tt+1]}
#pragma unroll
  for (int g = 0; g < 8; ++g) {
    float4 a = *(const float4*)(sx + g * 8);
    float4 b4 = *(const float4*)(sx + g * 8 + 4);
    xb[g * 4 + 0] = f32x2_t{a.x, a.y};
    xb[g * 4 + 1] = f32x2_t{a.z, a.w};
    xb[g * 4 + 2] = f32x2_t{b4.x, b4.y};
    xb[g * 4 + 3] = f32x2_t{b4.z, b4.w};
  }

  // B-fragment base: wave hq, frag (c*2+jh, hq*2+ih), lane offset l*8
  const __hip_bfloat16* pw = frag + (size_t)hq * 1024 + lane * 8;

  f32x4_t acc[2];
#pragma unroll
  for (int ih = 0; ih < 2; ++ih)
    acc[ih] = (f32x4_t)0.0f;

  // depth-1 prefetch buffer: slot jh*2+ih holds chunk-c frags during chunk c
  bf16x8_t b[4];
#pragma unroll
  for (int jh = 0; jh < 2; ++jh)
#pragma unroll
    for (int ih = 0; ih < 2; ++ih)
      b[jh * 2 + ih] = *(const bf16x8_t*)(pw + jh * 4096 + ih * 512);

#pragma unroll
  for (int c = 0; c < 36; ++c) {
    const int I = CI[c], J = CJ[c];
    bf16x8_t afrag[2];
#pragma unroll
    for (int jh = 0; jh < 2; ++jh) {
      float s = sx[I * 8 + jh * 4 + q];   // LDS b32, 2-way max conflict
      const f32x2_t s2 = f32x2_t{s, s};
      u32x4_t adv;
#pragma unroll
      for (int tt = 0; tt < 4; ++tt) {
        f32x2_t pr = s2 * xb[J * 4 + tt];          // v_pk_mul_f32
        u32x2_t u = __builtin_bit_cast(u32x2_t, pr);
        adv[tt] = __builtin_amdgcn_perm(u[1], u[0], 0x07060302);
      }
      afrag[jh] = __builtin_bit_cast(bf16x8_t, adv);
    }
    const __hip_bfloat16* pn = pw + (size_t)(c + 1) * 8192;
#pragma unroll
    for (int jh = 0; jh < 2; ++jh)
#pragma unroll
      for (int ih = 0; ih < 2; ++ih) {
        acc[ih] = __builtin_amdgcn_mfma_f32_16x16x32_bf16(
            afrag[jh], b[jh * 2 + ih], acc[ih], 0, 0, 0);
        // reload slot for chunk c+1 (issued right after the MFMA consumes it;
        // in-flight across the rest of this chunk's MFMAs + next afrag build)
        b[jh * 2 + ih] = *(const bf16x8_t*)(pn + jh * 4096 + ih * 512);
      }
  }

  // order-1 tail (chunk 36, b[] holds its frags): A = x_j straight from LDS
#pragma unroll
  for (int jh = 0; jh < 2; ++jh) {
    float4 a = *(const float4*)(sx + jh * 32 + q * 8);
    float4 b4 = *(const float4*)(sx + jh * 32 + q * 8 + 4);
    const float pr[4][2] = {{a.x, a.y}, {a.z, a.w}, {b4.x, b4.y}, {b4.z, b4.w}};
    u32x4_t adv;
#pragma unroll
    for (int tt = 0; tt < 4; ++tt)
      adv[tt] = __builtin_amdgcn_perm(__float_as_uint(pr[tt][1]),
                                      __float_as_uint(pr[tt][0]), 0x07060302);
    bf16x8_t af = __builtin_bit_cast(bf16x8_t, adv);
#pragma unroll
    for (int ih = 0; ih < 2; ++ih)
      acc[ih] = __builtin_amdgcn_mfma_f32_16x16x32_bf16(
          af, b[jh * 2 + ih], acc[ih], 0, 0, 0);
  }

  // epilogue: a += bias; hw cos (input in revolutions); product over h
  float bs[2];
#pragma unroll
  for (int ih = 0; ih < 2; ++ih)
    bs[ih] = biasg[hq * 32 + ih * 16 + c15];

  const float INV2PI = 0.15915494309189535f;
  float prod[4];
#pragma unroll
  for (int r = 0; r < 4; ++r) {
    float c0 = __builtin_amdgcn_cosf((acc[0][r] + bs[0]) * INV2PI);
    float c1 = __builtin_amdgcn_cosf((acc[1][r] + bs[1]) * INV2PI);
    prod[r] = c0 * c1;
  }

  // product across the 16 h-columns held by lanes (width-16 butterfly)
#pragma unroll
  for (int ofs = 1; ofs < 16; ofs <<= 1)
#pragma unroll
    for (int r = 0; r < 4; ++r)
      prod[r] *= __shfl_xor(prod[r], ofs, 16);

  if (c15 == 0) {
#pragma unroll
    for (int r = 0; r < 4; ++r)
      part[hq][wm * 16 + q * 4 + r] = prod[r];
  }
  __syncthreads();
  if (tid < 32) {
    float f = part[0][tid] * part[1][tid] * part[2][tid] * part[3][tid];
    outg[mblk + tid] = f;
  }
}

extern "C" void kernel_launch(void* const* d_in, const int* in_sizes, int n_in,
                              void* d_out, int out_size, void* d_ws, size_t ws_size,
                              hipStream_t stream) {
  const float* x   = (const float*)d_in[0];
  const float* w1f = (const float*)d_in[1];
  const float* w2f = (const float*)d_in[2];
  const float* hb  = (const float*)d_in[3];
  float* out = (float*)d_out;
  uint16_t* frag = (uint16_t*)d_ws;   // FRAG_ELEMS bf16 (592 KB)
  (void)in_sizes; (void)n_in; (void)out_size; (void)ws_size;

  cvt_kernel<<<148, 256, 0, stream>>>(w1f, w2f, frag);
  rbm_kernel<<<NB / 32, 512, 0, stream>>>(
      x, hb, (const __hip_bfloat16*)frag, out);
}